// Round 2
// 220.824 us; speedup vs baseline: 1.0012x; 1.0012x over previous
//
#include <hip/hip_runtime.h>
#include <math.h>

#define DEV_INLINE __device__ __forceinline__

// Native clang vector type: __builtin_nontemporal_* requires scalar or
// ext_vector types (HIP_vector_type float4 is a struct and is rejected).
typedef float fvec4 __attribute__((ext_vector_type(4)));

// Branch-free fast atan2. Max error ~1e-5 rad; output sensitivity to alpha is
// ~0.07 (2 iters x DT x MLP slope x chassis gains), so contributes ~1e-6 abs
// error vs 1.4e-2 threshold. atan2(0,0) -> NaN is measure-zero on this input.
DEV_INLINE float fast_atan2f(float y, float x) {
    const float kPI  = 3.14159265358979323846f;
    const float kPI2 = 1.57079632679489661923f;
    float ax = fabsf(x), ay = fabsf(y);
    float mx = fmaxf(ax, ay);
    float mn = fminf(ax, ay);
    float a  = mn * __builtin_amdgcn_rcpf(mx);
    float s  = a * a;
    float p  = -0.01172120f;
    p = fmaf(p, s,  0.05265332f);
    p = fmaf(p, s, -0.11643287f);
    p = fmaf(p, s,  0.19354346f);
    p = fmaf(p, s, -0.33262347f);
    p = fmaf(p, s,  0.99997726f);
    float r = a * p;                       // atan(mn/mx) in [0, pi/4]
    r = (ay > ax)   ? (kPI2 - r) : r;      // reflect across pi/4
    r = (x < 0.0f)  ? (kPI  - r) : r;      // reflect across pi/2
    return copysignf(r, y);
}

// 1 -> 12 -> 1 ReLU MLP: relu(a*w1 + b1) . w2 + b2
DEV_INLINE float mlp12(float a, const float* __restrict__ w1,
                       const float* __restrict__ b1,
                       const float* __restrict__ w2, float b2) {
    float acc = b2;
#pragma unroll
    for (int j = 0; j < 12; ++j) {
        float h = fmaxf(fmaf(a, w1[j], b1[j]), 0.0f);
        acc = fmaf(h, w2[j], acc);
    }
    return acc;
}

// 4 rows per thread: 8 independent dwordx4 loads in flight per wave (vs 2),
// 4 independent dynamics dependency chains interleaved by the scheduler,
// weight prologue amortized 4x, float4 nontemporal stores.
#define ROWS 4

__global__ __launch_bounds__(256) void dyn_kernel(
    const fvec4* __restrict__ x4,
    const float* __restrict__ fy_w1, const float* __restrict__ fy_b1,
    const float* __restrict__ fy_w2, const float* __restrict__ fy_b2,
    const float* __restrict__ ry_w1, const float* __restrict__ ry_b1,
    const float* __restrict__ ry_w2, const float* __restrict__ ry_b2,
    const float* __restrict__ rx_w, const float* __restrict__ rx_b,
    float* __restrict__ out, int nrows) {
    const float kLF     = 1.5f;
    const float kLR     = 1.4f;
    const float kCM1    = 550.0f;
    const float kCM2    = 650.0f;
    const float kDT     = 0.01f;
    const float kGRAV   = 9.8f;
    const float kCDRIVE = (float)(3.45 * 0.919 / (0.34 * 1265.0));
    const float kWF     = (float)(1265.0 * 1.5 / 2000.0);  // MASS*LF/IZ
    const float kWR     = (float)(1265.0 * 1.4 / 2000.0);  // MASS*LR/IZ

    __shared__ float sout[ROWS * 256 * 3];  // 12 KB block transpose buffer

    // ---- uniform weights (uniform addresses -> scalar loads) ----
    float fw1[12], fb1[12], fw2[12];
    float rw1[12], rb1[12], rw2[12];
#pragma unroll
    for (int j = 0; j < 12; ++j) {
        fw1[j] = fy_w1[j]; fb1[j] = fy_b1[j]; fw2[j] = fy_w2[j];
        rw1[j] = ry_w1[j]; rb1[j] = ry_b1[j]; rw2[j] = ry_w2[j];
    }
    const float fb2 = fy_b2[0];
    const float rb2 = ry_b2[0];
    const float rxw = rx_w[0];
    const float rxb = rx_b[0];

    const int tid = threadIdx.x;
    const long long base = (long long)blockIdx.x * (ROWS * 256);

    float o0[ROWS], o1[ROWS], o2[ROWS];

#pragma unroll
    for (int k = 0; k < ROWS; ++k) {
        const long long t = base + k * 256 + tid;
        float a0 = 0.0f, a1 = 0.0f, a2 = 0.0f;
        if (t < nrows) {
            // two 16B loads, lane stride 32B: every 32B sector consumed.
            // nontemporal: streamed once, keep out of L2 LRU.
            const fvec4 lo = __builtin_nontemporal_load(&x4[2 * t]);
            const fvec4 hi = __builtin_nontemporal_load(&x4[2 * t + 1]);

            const float pwm   = lo[0];
            const float theta = lo[2];
            const float x3    = lo[3];
            const float x4v   = hi[0];
            const float x5    = hi[1];
            const float pitch = hi[3];

            const float st = __sinf(theta);
            const float ct = __cosf(theta);
            const float sp = __sinf(pitch);
            const float a_pred = (pwm > 0.0f ? kCM1 : kCM2) * pwm * kCDRIVE;

#pragma unroll
            for (int it = 0; it < 2; ++it) {
                const float vx = x3 + a0;
                const float vy = x4v + a1;
                const float w  = x5 + a2;

                const float af = theta - fast_atan2f(fmaf(w, kLF, vy), vx);
                const float ar = fast_atan2f(fmaf(w, kLR, -vy), vx);

                // where(a > 0, f(a), -f(-a)) == s * f(s*a), s = sign
                const float sf  = af > 0.0f ? 1.0f : -1.0f;
                const float Ffy = sf * mlp12(sf * af, fw1, fb1, fw2, fb2);
                const float sr  = ar > 0.0f ? 1.0f : -1.0f;
                const float Fry = sr * mlp12(sr * ar, rw1, rb1, rw2, rb2);

                const float Frx = fmaf(rxw * vx, vx, a_pred + rxb);

                const float vx_dot = Frx - Ffy * st + vy * w - kGRAV * sp;
                const float vy_dot = Fry + Ffy * ct - vx * w;
                const float w_dot  = kWF * Ffy * ct - kWR * Fry;

                a0 = fmaf(kDT, vx_dot, a0);
                a1 = fmaf(kDT, vy_dot, a1);
                a2 = fmaf(kDT, w_dot,  a2);
            }
        }
        o0[k] = a0; o1[k] = a1; o2[k] = a2;
    }

    // ---- LDS transpose: write stride-3 (2-way bank alias = free), read
    // float4-contiguous, then lane-contiguous nontemporal dwordx4 stores ----
#pragma unroll
    for (int k = 0; k < ROWS; ++k) {
        const int r = k * 256 + tid;
        sout[r * 3 + 0] = o0[k];
        sout[r * 3 + 1] = o1[k];
        sout[r * 3 + 2] = o2[k];
    }
    __syncthreads();

    const long long gbase = base * 3;
    const long long gmax  = (long long)nrows * 3;
    if (base + ROWS * 256 <= (long long)nrows) {
        // full block fast path: ROWS*256*3 = 3072 floats = 768 float4,
        // 3 float4 per thread, 16B-aligned (gbase*4 = 12288*blockIdx bytes)
        const fvec4* s4 = (const fvec4*)sout;
        fvec4* o4 = (fvec4*)(out + gbase);
#pragma unroll
        for (int j = 0; j < (ROWS * 3) / 4; ++j) {
            __builtin_nontemporal_store(s4[j * 256 + tid], &o4[j * 256 + tid]);
        }
    } else {
        // tail block: scalar guarded stores
#pragma unroll
        for (int j = 0; j < ROWS * 3; ++j) {
            const long long gi = gbase + j * 256 + tid;
            if (gi < gmax) out[gi] = sout[j * 256 + tid];
        }
    }
}

extern "C" void kernel_launch(void* const* d_in, const int* in_sizes, int n_in,
                              void* d_out, int out_size, void* d_ws, size_t ws_size,
                              hipStream_t stream) {
    const fvec4* x4    = (const fvec4*)d_in[0];
    const float* fy_w1 = (const float*)d_in[1];
    const float* fy_b1 = (const float*)d_in[2];
    const float* fy_w2 = (const float*)d_in[3];
    const float* fy_b2 = (const float*)d_in[4];
    const float* ry_w1 = (const float*)d_in[5];
    const float* ry_b1 = (const float*)d_in[6];
    const float* ry_w2 = (const float*)d_in[7];
    const float* ry_b2 = (const float*)d_in[8];
    const float* rx_w  = (const float*)d_in[9];
    const float* rx_b  = (const float*)d_in[10];

    const int nrows = in_sizes[0] / 8;
    const int threads = 256;
    const int rows_per_block = threads * ROWS;
    const int blocks = (nrows + rows_per_block - 1) / rows_per_block;

    dyn_kernel<<<blocks, threads, 0, stream>>>(
        x4, fy_w1, fy_b1, fy_w2, fy_b2, ry_w1, ry_b1, ry_w2, ry_b2, rx_w, rx_b,
        (float*)d_out, nrows);
}